// Round 14
// baseline (352.054 us; speedup 1.0000x reference)
//
#include <hip/hip_runtime.h>

#define TSEQ 4096
#define DM 768
#define NHEAD 12
#define HDIM 64
#define SC 0.1803368801111204f  // (1/sqrt(64)) * log2(e)

using f32x4  = __attribute__((ext_vector_type(4))) float;
using bf16x8 = __attribute__((ext_vector_type(8))) short;
using bf16x4 = __attribute__((ext_vector_type(4))) short;

// Barrier that waits only LDS ops — global stores stay in flight (no vmcnt(0)
// drain; the T4 "never vmcnt(0) in the main loop" rule).
#define LGKM_BARRIER() asm volatile("s_waitcnt lgkmcnt(0)\n\ts_barrier" ::: "memory")

__device__ __forceinline__ short f2bf(float f) {
    union { float f; unsigned u; } x; x.f = f;
    unsigned r = x.u + 0x7FFFu + ((x.u >> 16) & 1u);  // RNE; inputs finite
    return (short)(r >> 16);
}

// hardware packed f32x2 -> bf16x2 (RNE), 1 inst for 2 conversions
__device__ __forceinline__ unsigned pk2(float lo, float hi) {
    unsigned d;
    asm("v_cvt_pk_bf16_f32 %0, %1, %2" : "=v"(d) : "v"(lo), "v"(hi));
    return d;
}

__device__ __forceinline__ bf16x8 pack8(f32x4 a, f32x4 b) {
    union { unsigned u[4]; bf16x8 v; } r;
    r.u[0] = pk2(a[0], a[1]); r.u[1] = pk2(a[2], a[3]);
    r.u[2] = pk2(b[0], b[1]); r.u[3] = pk2(b[2], b[3]);
    return r.v;
}

__device__ __forceinline__ f32x4 mfma16(bf16x8 a, bf16x8 b, f32x4 c) {
    return __builtin_amdgcn_mfma_f32_16x16x32_bf16(a, b, c, 0, 0, 0);
}

// ---------------- fused QKV projection GEMMs (unchanged from round 7) -------
__global__ __launch_bounds__(512) void gemm_qkv(
    const float* __restrict__ q_in, const float* __restrict__ k_in,
    const float* __restrict__ v_in,
    const float* __restrict__ Wq_w, const float* __restrict__ Wq_b,
    const float* __restrict__ Wk_w, const float* __restrict__ Wk_b,
    const float* __restrict__ Wv_w, const float* __restrict__ Wv_b,
    short* __restrict__ Qb, short* __restrict__ Kb, short* __restrict__ Vt)
{
    constexpr int K = DM;
    __shared__ __align__(16) short As[64 * 72];    // 9.2 KB
    __shared__ __align__(16) short Bs[256 * 72];   // 36.9 KB

    const int D = blockIdx.x;
    const int o = (D & 7) * 72 + (D >> 3);
    const int bm = (o & 63) * 64;
    const int g  = o >> 6;
    const int bn = (g % 3) * 256;
    const int z  = g / 3;

    const float* A    = (z == 0) ? q_in : (z == 1) ? k_in : v_in;
    const float* W    = (z == 0) ? Wq_w : (z == 1) ? Wk_w : Wv_w;
    const float* bias = (z == 0) ? Wq_b : (z == 1) ? Wk_b : Wv_b;

    const int tid = threadIdx.x;
    const int wid = tid >> 6;
    const int lane = tid & 63;
    const int wm = wid >> 2, wn = wid & 3;
    const int l15 = lane & 15, lq = lane >> 4;

    f32x4 acc[2][4] = {};
    const int sr = tid >> 3;
    const int sc = (tid & 7) * 8;

    for (int k0 = 0; k0 < K; k0 += 64) {
        {
            const float* ga = A + (size_t)(bm + sr) * K + k0 + sc;
            *(bf16x8*)&As[sr * 72 + sc] =
                pack8(*(const f32x4*)ga, *(const f32x4*)(ga + 4));
        }
        #pragma unroll
        for (int it = 0; it < 4; ++it) {
            int r = sr + it * 64;
            const float* gb = W + (size_t)(bn + r) * K + k0 + sc;
            *(bf16x8*)&Bs[r * 72 + sc] =
                pack8(*(const f32x4*)gb, *(const f32x4*)(gb + 4));
        }
        LGKM_BARRIER();
        __builtin_amdgcn_s_setprio(1);
        #pragma unroll
        for (int ks = 0; ks < 2; ++ks) {
            bf16x8 af0 = *(bf16x8*)&As[(wm * 32 + l15) * 72 + ks * 32 + lq * 8];
            bf16x8 af1 = *(bf16x8*)&As[(wm * 32 + 16 + l15) * 72 + ks * 32 + lq * 8];
            #pragma unroll
            for (int n = 0; n < 4; ++n) {
                bf16x8 bfv = *(bf16x8*)&Bs[(wn * 64 + n * 16 + l15) * 72 + ks * 32 + lq * 8];
                acc[0][n] = mfma16(af0, bfv, acc[0][n]);
                acc[1][n] = mfma16(af1, bfv, acc[1][n]);
            }
        }
        __builtin_amdgcn_s_setprio(0);
        LGKM_BARRIER();
    }

    #pragma unroll
    for (int mf = 0; mf < 2; ++mf) {
        const int row0 = bm + wm * 32 + mf * 16 + lq * 4;
        #pragma unroll
        for (int n = 0; n < 4; ++n) {
            int col = bn + wn * 64 + n * 16 + l15;
            float b = bias[col];
            if (z == 2) {
                uint2 pv;
                pv.x = pk2(acc[mf][n][0] + b, acc[mf][n][1] + b);
                pv.y = pk2(acc[mf][n][2] + b, acc[mf][n][3] + b);
                *(uint2*)(Vt + (size_t)col * TSEQ + row0) = pv;
            } else {
                short* dst = (z == 0) ? Qb : Kb;
                #pragma unroll
                for (int r = 0; r < 4; ++r)
                    dst[(size_t)(row0 + r) * DM + col] = f2bf(acc[mf][n][r] + b);
            }
        }
    }
}

// ---------------- output GEMM (unchanged from round 7) ----------------------
__global__ __launch_bounds__(512) void gemm_out(
    const float* __restrict__ A, const float* __restrict__ W,
    const float* __restrict__ bias, float* __restrict__ Cout)
{
    constexpr int K = DM;
    __shared__ __align__(16) short As[64 * 72];
    __shared__ __align__(16) short Bs[256 * 72];

    const int D = blockIdx.x;
    const int o = (D & 7) * 24 + (D >> 3);
    const int bm = (o & 63) * 64;
    const int bn = (o >> 6) * 256;

    const int tid = threadIdx.x;
    const int wid = tid >> 6;
    const int lane = tid & 63;
    const int wm = wid >> 2, wn = wid & 3;
    const int l15 = lane & 15, lq = lane >> 4;

    f32x4 acc[2][4] = {};
    const int sr = tid >> 3;
    const int sc = (tid & 7) * 8;

    for (int k0 = 0; k0 < K; k0 += 64) {
        {
            const float* ga = A + (size_t)(bm + sr) * K + k0 + sc;
            *(bf16x8*)&As[sr * 72 + sc] =
                pack8(*(const f32x4*)ga, *(const f32x4*)(ga + 4));
        }
        #pragma unroll
        for (int it = 0; it < 4; ++it) {
            int r = sr + it * 64;
            const float* gb = W + (size_t)(bn + r) * K + k0 + sc;
            *(bf16x8*)&Bs[r * 72 + sc] =
                pack8(*(const f32x4*)gb, *(const f32x4*)(gb + 4));
        }
        LGKM_BARRIER();
        __builtin_amdgcn_s_setprio(1);
        #pragma unroll
        for (int ks = 0; ks < 2; ++ks) {
            bf16x8 af0 = *(bf16x8*)&As[(wm * 32 + l15) * 72 + ks * 32 + lq * 8];
            bf16x8 af1 = *(bf16x8*)&As[(wm * 32 + 16 + l15) * 72 + ks * 32 + lq * 8];
            #pragma unroll
            for (int n = 0; n < 4; ++n) {
                bf16x8 bfv = *(bf16x8*)&Bs[(wn * 64 + n * 16 + l15) * 72 + ks * 32 + lq * 8];
                acc[0][n] = mfma16(af0, bfv, acc[0][n]);
                acc[1][n] = mfma16(af1, bfv, acc[1][n]);
            }
        }
        __builtin_amdgcn_s_setprio(0);
        LGKM_BARRIER();
    }

    #pragma unroll
    for (int mf = 0; mf < 2; ++mf) {
        const int row0 = bm + wm * 32 + mf * 16 + lq * 4;
        #pragma unroll
        for (int n = 0; n < 4; ++n) {
            int col = bn + wn * 64 + n * 16 + l15;
            float b = bias[col];
            #pragma unroll
            for (int r = 0; r < 4; ++r)
                Cout[(size_t)(row0 + r) * DM + col] = acc[mf][n][r] + b;
        }
    }
}

// ---------------- fused causal attention (V-in-regs, 4 blocks/CU) -----------
// Flat grid 768, 256 threads (4 waves, 16 q-rows each), balanced qt map.
// Phase 2: V^T fragments load DIRECTLY from global into per-wave registers
// (issued after QK^T, consumed after the exp/store section — latency hidden);
// Ps is per-wave so only the Ks double-buffer needs the per-step barrier.
// LDS pool 36.9 KB (phase-1 chunks) -> 4 blocks/CU = 16 waves (was 12).
__global__ __launch_bounds__(256, 4) void attn_fused(
    const short* __restrict__ Qb, const short* __restrict__ Kb,
    const short* __restrict__ Vt, float* __restrict__ Wout,
    float* __restrict__ AttnO)
{
    const int bid = blockIdx.x;
    const int j = bid & 63;
    const int s = bid >> 8;                  // co-resident segment 0..2
    const int h = s * 4 + ((bid >> 6) & 3);  // head 0..11
    const int qt = (s == 0) ? j
                 : (s == 1) ? ((j + 32) & 63)
                 : ((j < 32) ? 62 - 2 * j : 127 - 2 * j);  // magic rectangle
    const int q0 = qt * 64;
    const int tid = threadIdx.x, wid = tid >> 6, lane = tid & 63;
    const int l15 = lane & 15, lq = lane >> 4;

    // pool: phase1 [2][128*72] shorts = 36.9KB (the max);
    // phase2 aliases Ks2[2][64*72] (18.4KB) + Ps[4][16*72] (9.2KB)
    __shared__ __align__(16) short lds[18432];

    const int nkt = qt + 1;

    // ---- zero strict-upper tail (NT stores: pure streaming) ----
    {
        float* wbase = Wout + (size_t)h * TSEQ * TSEQ + (size_t)(q0 + wid * 16) * TSEQ;
        f32x4 z = {0.f, 0.f, 0.f, 0.f};
        for (int kt = nkt; kt < 64; ++kt) {
            #pragma unroll
            for (int i = 0; i < 4; ++i)
                __builtin_nontemporal_store(
                    z, (f32x4*)(wbase + (size_t)(lq + i * 4) * TSEQ + kt * 64 + l15 * 4));
        }
    }

    // Q as MFMA B-operand: q-row = lane&15, k = (lane>>4)*8
    const short* qp = Qb + (size_t)(q0 + wid * 16 + l15) * DM + h * HDIM + lq * 8;
    bf16x8 qf0 = *(const bf16x8*)qp;
    bf16x8 qf1 = *(const bf16x8*)(qp + 32);

    const short* kbase = Kb + (size_t)h * HDIM;        // + k_row * DM
    const short* vbase = Vt + (size_t)h * HDIM * TSEQ; // + hd_row * TSEQ
    const int myq = q0 + wid * 16 + l15;

    const int srow = tid >> 3;          // 0..31
    const int scol = (tid & 7) * 8;     // 0..56

    // ---- phase 1: row sums of exp; K staged in 128-row chunks ----
    const int nch = (nkt + 1) >> 1;
    auto stageKbig = [&](int c, int b) {
        const int base_k = c * 128;
        const int iters = (nkt * 64 - base_k) >= 128 ? 4 : 2;
        short* dst = lds + b * (128 * 72);
        for (int it = 0; it < iters; ++it) {
            int r = srow + it * 32;
            *(bf16x8*)&dst[r * 72 + scol] =
                *(const bf16x8*)&kbase[(size_t)(base_k + r) * DM + scol];
        }
    };

    f32x4 lacc = {0.f, 0.f, 0.f, 0.f};
    stageKbig(0, 0);
    LGKM_BARRIER();
    for (int c = 0; c < nch; ++c) {
        const int b = c & 1;
        if (c + 1 < nch) stageKbig(c + 1, b ^ 1);
        const short* kb = lds + b * (128 * 72);
        #pragma unroll
        for (int t = 0; t < 2; ++t) {
            const int kt = c * 2 + t;
            if (kt >= nkt) break;
            f32x4 s4[4] = {};
            __builtin_amdgcn_s_setprio(1);
            #pragma unroll
            for (int ks = 0; ks < 2; ++ks) {
                bf16x8 qf = ks ? qf1 : qf0;
                #pragma unroll
                for (int n = 0; n < 4; ++n) {
                    bf16x8 kf = *(const bf16x8*)
                        &kb[(t * 64 + n * 16 + l15) * 72 + ks * 32 + lq * 8];
                    s4[n] = mfma16(kf, qf, s4[n]);
                }
            }
            __builtin_amdgcn_s_setprio(0);
            if (kt == qt) {  // diagonal: mask k > q
                #pragma unroll
                for (int n = 0; n < 4; ++n) {
                    int kb0 = kt * 64 + n * 16 + lq * 4;
                    #pragma unroll
                    for (int r = 0; r < 4; ++r)
                        lacc[n] += (kb0 + r <= myq) ? exp2f(s4[n][r] * SC) : 0.f;
                }
            } else {
                #pragma unroll
                for (int n = 0; n < 4; ++n)
                    #pragma unroll
                    for (int r = 0; r < 4; ++r)
                        lacc[n] += exp2f(s4[n][r] * SC);
            }
        }
        LGKM_BARRIER();
    }
    float lsum = (lacc[0] + lacc[1]) + (lacc[2] + lacc[3]);
    lsum += __shfl_xor(lsum, 16);
    lsum += __shfl_xor(lsum, 32);
    const float nlog = -__log2f(lsum);   // fold 1/lsum into the exponent

    // ---- phase 2: recompute S, weight stores, P@V (V direct from global) ---
    short* Ks2 = lds;                               // [2][64*72]
    short* Psw = lds + 2 * 64 * 72 + wid * (16 * 72);

    bf16x8 krg0, krg1;                  // staged K tile (named: rule #20)
    auto loadK = [&](int kt) {
        krg0 = *(const bf16x8*)&kbase[(size_t)(kt * 64 + srow) * DM + scol];
        krg1 = *(const bf16x8*)&kbase[(size_t)(kt * 64 + srow + 32) * DM + scol];
    };
    auto writeK = [&](int b) {
        short* kd = Ks2 + b * (64 * 72);
        *(bf16x8*)&kd[srow * 72 + scol] = krg0;
        *(bf16x8*)&kd[(srow + 32) * 72 + scol] = krg1;
    };

    float* wq = Wout + (size_t)h * TSEQ * TSEQ + (size_t)myq * TSEQ;
    f32x4 o[4] = {};
    loadK(0);
    writeK(0);
    LGKM_BARRIER();
    for (int kt = 0; kt < nkt; ++kt) {
        const int b = kt & 1;
        const bool more = (kt + 1 < nkt);
        if (more) {
            loadK(kt + 1);                        // issue next K early
            __builtin_amdgcn_sched_barrier(0);    // pin: loads above compute
        }
        f32x4 s4[4] = {};
        __builtin_amdgcn_s_setprio(1);
        #pragma unroll
        for (int ks = 0; ks < 2; ++ks) {
            bf16x8 qf = ks ? qf1 : qf0;
            #pragma unroll
            for (int n = 0; n < 4; ++n) {
                bf16x8 kf = *(const bf16x8*)
                    &Ks2[b * (64 * 72) + (n * 16 + l15) * 72 + ks * 32 + lq * 8];
                s4[n] = mfma16(kf, qf, s4[n]);
            }
        }
        __builtin_amdgcn_s_setprio(0);
        // V^T fragments for this tile, direct from global (L2/L3-resident);
        // issued here, consumed after the exp/store section (~300cy away).
        const short* vkt = vbase + kt * 64 + lq * 8;
        bf16x8 vfa0 = *(const bf16x8*)&vkt[(size_t)(l15)      * TSEQ];
        bf16x8 vfa1 = *(const bf16x8*)&vkt[(size_t)(16 + l15) * TSEQ];
        bf16x8 vfa2 = *(const bf16x8*)&vkt[(size_t)(32 + l15) * TSEQ];
        bf16x8 vfa3 = *(const bf16x8*)&vkt[(size_t)(48 + l15) * TSEQ];
        bf16x8 vfb0 = *(const bf16x8*)&vkt[(size_t)(l15)      * TSEQ + 32];
        bf16x8 vfb1 = *(const bf16x8*)&vkt[(size_t)(16 + l15) * TSEQ + 32];
        bf16x8 vfb2 = *(const bf16x8*)&vkt[(size_t)(32 + l15) * TSEQ + 32];
        bf16x8 vfb3 = *(const bf16x8*)&vkt[(size_t)(48 + l15) * TSEQ + 32];

        const bool diag = (kt == qt);
        #pragma unroll
        for (int n = 0; n < 4; ++n) {
            const int kb0 = kt * 64 + n * 16 + lq * 4;
            f32x4 p;
            #pragma unroll
            for (int r = 0; r < 4; ++r) {
                float e = exp2f(fmaf(s4[n][r], SC, nlog));  // normalized
                p[r] = (diag && (kb0 + r > myq)) ? 0.f : e;
            }
            *(f32x4*)(wq + kb0) = p;              // plain store: L2-merged
            uint2 pv;
            pv.x = pk2(p[0], p[1]);
            pv.y = pk2(p[2], p[3]);
            *(uint2*)&Psw[l15 * 72 + n * 16 + lq * 4] = pv;
        }
        // P @ V: A-frag = P (q rows) from per-wave Ps (no barrier needed),
        // B-frag = V^T fragments already in registers.
        __builtin_amdgcn_s_setprio(1);
        {
            bf16x8 pf0 = *(bf16x8*)&Psw[l15 * 72 + lq * 8];
            bf16x8 pf1 = *(bf16x8*)&Psw[l15 * 72 + 32 + lq * 8];
            o[0] = mfma16(pf0, vfa0, o[0]);
            o[1] = mfma16(pf0, vfa1, o[1]);
            o[2] = mfma16(pf0, vfa2, o[2]);
            o[3] = mfma16(pf0, vfa3, o[3]);
            o[0] = mfma16(pf1, vfb0, o[0]);
            o[1] = mfma16(pf1, vfb1, o[1]);
            o[2] = mfma16(pf1, vfb2, o[2]);
            o[3] = mfma16(pf1, vfb3, o[3]);
        }
        __builtin_amdgcn_s_setprio(0);
        if (more) {
            __builtin_amdgcn_sched_barrier(0);    // pin: ds_write after PV
            writeK(b ^ 1);                        // reg -> LDS, no vmcnt(0)
        }
        LGKM_BARRIER();
    }

    // ---- epilogue: O (row = q0+wid*16+lq*4+r, col = h*64+n*16+l15) ----
    #pragma unroll
    for (int n = 0; n < 4; ++n) {
        int col = h * HDIM + n * 16 + l15;
        #pragma unroll
        for (int r = 0; r < 4; ++r) {
            int row = q0 + wid * 16 + lq * 4 + r;
            AttnO[(size_t)row * DM + col] = o[n][r];
        }
    }
}

extern "C" void kernel_launch(void* const* d_in, const int* in_sizes, int n_in,
                              void* d_out, int out_size, void* d_ws, size_t ws_size,
                              hipStream_t stream)
{
    const float* q_in = (const float*)d_in[0];
    const float* k_in = (const float*)d_in[1];
    const float* v_in = (const float*)d_in[2];
    // d_in[3] = causal mask (triu, k=1) — structure known, not read
    const float* Wq_w = (const float*)d_in[4];
    const float* Wq_b = (const float*)d_in[5];
    const float* Wk_w = (const float*)d_in[6];
    const float* Wk_b = (const float*)d_in[7];
    const float* Wv_w = (const float*)d_in[8];
    const float* Wv_b = (const float*)d_in[9];
    const float* W0_w = (const float*)d_in[10];
    const float* W0_b = (const float*)d_in[11];

    float* out  = (float*)d_out;                       // [4096][768] fp32
    float* wout = out + (size_t)TSEQ * DM;             // [12][4096][4096] fp32

    short* Qb = (short*)d_ws;                          // [4096][768] bf16
    short* Kb = Qb + (size_t)TSEQ * DM;                // [4096][768] bf16
    short* Vt = Kb + (size_t)TSEQ * DM;                // [768][4096] bf16 (V^T)
    float* AttnO = (float*)(Vt + (size_t)TSEQ * DM);   // [4096][768] fp32

    gemm_qkv<<<576, 512, 0, stream>>>(
        q_in, k_in, v_in, Wq_w, Wq_b, Wk_w, Wk_b, Wv_w, Wv_b, Qb, Kb, Vt);
    attn_fused<<<768, 256, 0, stream>>>(Qb, Kb, Vt, wout, AttnO);
    gemm_out<<<192, 512, 0, stream>>>(AttnO, W0_w, W0_b, out);
}

// Round 15
// 299.928 us; speedup vs baseline: 1.1738x; 1.1738x over previous
//
#include <hip/hip_runtime.h>

#define TSEQ 4096
#define DM 768
#define NHEAD 12
#define HDIM 64
#define SC 0.1803368801111204f  // (1/sqrt(64)) * log2(e)

using f32x4  = __attribute__((ext_vector_type(4))) float;
using bf16x8 = __attribute__((ext_vector_type(8))) short;
using bf16x4 = __attribute__((ext_vector_type(4))) short;

// Barrier that waits only LDS ops — global stores stay in flight (no vmcnt(0)
// drain; the T4 "never vmcnt(0) in the main loop" rule).
#define LGKM_BARRIER() asm volatile("s_waitcnt lgkmcnt(0)\n\ts_barrier" ::: "memory")

__device__ __forceinline__ short f2bf(float f) {
    union { float f; unsigned u; } x; x.f = f;
    unsigned r = x.u + 0x7FFFu + ((x.u >> 16) & 1u);  // RNE; inputs finite
    return (short)(r >> 16);
}

// hardware packed f32x2 -> bf16x2 (RNE), 1 inst for 2 conversions
__device__ __forceinline__ unsigned pk2(float lo, float hi) {
    unsigned d;
    asm("v_cvt_pk_bf16_f32 %0, %1, %2" : "=v"(d) : "v"(lo), "v"(hi));
    return d;
}

__device__ __forceinline__ bf16x8 pack8(f32x4 a, f32x4 b) {
    union { unsigned u[4]; bf16x8 v; } r;
    r.u[0] = pk2(a[0], a[1]); r.u[1] = pk2(a[2], a[3]);
    r.u[2] = pk2(b[0], b[1]); r.u[3] = pk2(b[2], b[3]);
    return r.v;
}

__device__ __forceinline__ f32x4 mfma16(bf16x8 a, bf16x8 b, f32x4 c) {
    return __builtin_amdgcn_mfma_f32_16x16x32_bf16(a, b, c, 0, 0, 0);
}

// ---------------- fused QKV projection GEMMs (unchanged from round 7) -------
__global__ __launch_bounds__(512) void gemm_qkv(
    const float* __restrict__ q_in, const float* __restrict__ k_in,
    const float* __restrict__ v_in,
    const float* __restrict__ Wq_w, const float* __restrict__ Wq_b,
    const float* __restrict__ Wk_w, const float* __restrict__ Wk_b,
    const float* __restrict__ Wv_w, const float* __restrict__ Wv_b,
    short* __restrict__ Qb, short* __restrict__ Kb, short* __restrict__ Vt)
{
    constexpr int K = DM;
    __shared__ __align__(16) short As[64 * 72];    // 9.2 KB
    __shared__ __align__(16) short Bs[256 * 72];   // 36.9 KB

    const int D = blockIdx.x;
    const int o = (D & 7) * 72 + (D >> 3);
    const int bm = (o & 63) * 64;
    const int g  = o >> 6;
    const int bn = (g % 3) * 256;
    const int z  = g / 3;

    const float* A    = (z == 0) ? q_in : (z == 1) ? k_in : v_in;
    const float* W    = (z == 0) ? Wq_w : (z == 1) ? Wk_w : Wv_w;
    const float* bias = (z == 0) ? Wq_b : (z == 1) ? Wk_b : Wv_b;

    const int tid = threadIdx.x;
    const int wid = tid >> 6;
    const int lane = tid & 63;
    const int wm = wid >> 2, wn = wid & 3;
    const int l15 = lane & 15, lq = lane >> 4;

    f32x4 acc[2][4] = {};
    const int sr = tid >> 3;
    const int sc = (tid & 7) * 8;

    for (int k0 = 0; k0 < K; k0 += 64) {
        {
            const float* ga = A + (size_t)(bm + sr) * K + k0 + sc;
            *(bf16x8*)&As[sr * 72 + sc] =
                pack8(*(const f32x4*)ga, *(const f32x4*)(ga + 4));
        }
        #pragma unroll
        for (int it = 0; it < 4; ++it) {
            int r = sr + it * 64;
            const float* gb = W + (size_t)(bn + r) * K + k0 + sc;
            *(bf16x8*)&Bs[r * 72 + sc] =
                pack8(*(const f32x4*)gb, *(const f32x4*)(gb + 4));
        }
        LGKM_BARRIER();
        __builtin_amdgcn_s_setprio(1);
        #pragma unroll
        for (int ks = 0; ks < 2; ++ks) {
            bf16x8 af0 = *(bf16x8*)&As[(wm * 32 + l15) * 72 + ks * 32 + lq * 8];
            bf16x8 af1 = *(bf16x8*)&As[(wm * 32 + 16 + l15) * 72 + ks * 32 + lq * 8];
            #pragma unroll
            for (int n = 0; n < 4; ++n) {
                bf16x8 bfv = *(bf16x8*)&Bs[(wn * 64 + n * 16 + l15) * 72 + ks * 32 + lq * 8];
                acc[0][n] = mfma16(af0, bfv, acc[0][n]);
                acc[1][n] = mfma16(af1, bfv, acc[1][n]);
            }
        }
        __builtin_amdgcn_s_setprio(0);
        LGKM_BARRIER();
    }

    #pragma unroll
    for (int mf = 0; mf < 2; ++mf) {
        const int row0 = bm + wm * 32 + mf * 16 + lq * 4;
        #pragma unroll
        for (int n = 0; n < 4; ++n) {
            int col = bn + wn * 64 + n * 16 + l15;
            float b = bias[col];
            if (z == 2) {
                uint2 pv;
                pv.x = pk2(acc[mf][n][0] + b, acc[mf][n][1] + b);
                pv.y = pk2(acc[mf][n][2] + b, acc[mf][n][3] + b);
                *(uint2*)(Vt + (size_t)col * TSEQ + row0) = pv;
            } else {
                short* dst = (z == 0) ? Qb : Kb;
                #pragma unroll
                for (int r = 0; r < 4; ++r)
                    dst[(size_t)(row0 + r) * DM + col] = f2bf(acc[mf][n][r] + b);
            }
        }
    }
}

// ---------------- output GEMM (unchanged from round 7) ----------------------
__global__ __launch_bounds__(512) void gemm_out(
    const float* __restrict__ A, const float* __restrict__ W,
    const float* __restrict__ bias, float* __restrict__ Cout)
{
    constexpr int K = DM;
    __shared__ __align__(16) short As[64 * 72];
    __shared__ __align__(16) short Bs[256 * 72];

    const int D = blockIdx.x;
    const int o = (D & 7) * 24 + (D >> 3);
    const int bm = (o & 63) * 64;
    const int bn = (o >> 6) * 256;

    const int tid = threadIdx.x;
    const int wid = tid >> 6;
    const int lane = tid & 63;
    const int wm = wid >> 2, wn = wid & 3;
    const int l15 = lane & 15, lq = lane >> 4;

    f32x4 acc[2][4] = {};
    const int sr = tid >> 3;
    const int sc = (tid & 7) * 8;

    for (int k0 = 0; k0 < K; k0 += 64) {
        {
            const float* ga = A + (size_t)(bm + sr) * K + k0 + sc;
            *(bf16x8*)&As[sr * 72 + sc] =
                pack8(*(const f32x4*)ga, *(const f32x4*)(ga + 4));
        }
        #pragma unroll
        for (int it = 0; it < 4; ++it) {
            int r = sr + it * 64;
            const float* gb = W + (size_t)(bn + r) * K + k0 + sc;
            *(bf16x8*)&Bs[r * 72 + sc] =
                pack8(*(const f32x4*)gb, *(const f32x4*)(gb + 4));
        }
        LGKM_BARRIER();
        __builtin_amdgcn_s_setprio(1);
        #pragma unroll
        for (int ks = 0; ks < 2; ++ks) {
            bf16x8 af0 = *(bf16x8*)&As[(wm * 32 + l15) * 72 + ks * 32 + lq * 8];
            bf16x8 af1 = *(bf16x8*)&As[(wm * 32 + 16 + l15) * 72 + ks * 32 + lq * 8];
            #pragma unroll
            for (int n = 0; n < 4; ++n) {
                bf16x8 bfv = *(bf16x8*)&Bs[(wn * 64 + n * 16 + l15) * 72 + ks * 32 + lq * 8];
                acc[0][n] = mfma16(af0, bfv, acc[0][n]);
                acc[1][n] = mfma16(af1, bfv, acc[1][n]);
            }
        }
        __builtin_amdgcn_s_setprio(0);
        LGKM_BARRIER();
    }

    #pragma unroll
    for (int mf = 0; mf < 2; ++mf) {
        const int row0 = bm + wm * 32 + mf * 16 + lq * 4;
        #pragma unroll
        for (int n = 0; n < 4; ++n) {
            int col = bn + wn * 64 + n * 16 + l15;
            float b = bias[col];
            #pragma unroll
            for (int r = 0; r < 4; ++r)
                Cout[(size_t)(row0 + r) * DM + col] = acc[mf][n][r] + b;
        }
    }
}

// ---------------- fused causal attention (r9 base + overlap fixes) ----------
// Flat grid 768, 256 threads (4 waves, 16 q-rows each), balanced qt map.
// Changes vs r9: (1) upper-triangle zero-fill interleaved INTO phase 1 so the
// write pipe works during the compute-only phase; (2) Vs single-buffered
// (PV is the last reader; barrier already follows) -> LDS 46 -> 36.9 KB ->
// 4 blocks/CU = 16 waves; (3) launch_bounds(256,4) pins VGPR <= 128.
__global__ __launch_bounds__(256, 4) void attn_fused(
    const short* __restrict__ Qb, const short* __restrict__ Kb,
    const short* __restrict__ Vt, float* __restrict__ Wout,
    float* __restrict__ AttnO)
{
    const int bid = blockIdx.x;
    const int j = bid & 63;
    const int s = bid >> 8;                  // co-resident segment 0..2
    const int h = s * 4 + ((bid >> 6) & 3);  // head 0..11
    const int qt = (s == 0) ? j
                 : (s == 1) ? ((j + 32) & 63)
                 : ((j < 32) ? 62 - 2 * j : 127 - 2 * j);  // magic rectangle
    const int q0 = qt * 64;
    const int tid = threadIdx.x, wid = tid >> 6, lane = tid & 63;
    const int l15 = lane & 15, lq = lane >> 4;

    // pool 36864 B, aliased: phase1 K-chunks [2][128*72];
    // phase2 Ks2[2][64*72] + Vs[64*72] + Ps[4][16*72]
    __shared__ __align__(16) short lds[18432];

    const int nkt = qt + 1;

    // Q as MFMA B-operand: q-row = lane&15, k = (lane>>4)*8
    const short* qp = Qb + (size_t)(q0 + wid * 16 + l15) * DM + h * HDIM + lq * 8;
    bf16x8 qf0 = *(const bf16x8*)qp;
    bf16x8 qf1 = *(const bf16x8*)(qp + 32);

    const short* kbase = Kb + (size_t)h * HDIM;        // + k_row * DM
    const short* vbase = Vt + (size_t)h * HDIM * TSEQ; // + hd_row * TSEQ
    const int myq = q0 + wid * 16 + l15;

    const int srow = tid >> 3;          // 0..31
    const int scol = (tid & 7) * 8;     // 0..56

    // ---- phase 1: row sums of exp; K staged in 128-row chunks.
    //      Upper-triangle zero-fill interleaved per chunk (write||compute). --
    const int nch = (nkt + 1) >> 1;
    auto stageKbig = [&](int c, int b) {
        const int base_k = c * 128;
        const int iters = (nkt * 64 - base_k) >= 128 ? 4 : 2;
        short* dst = lds + b * (128 * 72);
        for (int it = 0; it < iters; ++it) {
            int r = srow + it * 32;
            *(bf16x8*)&dst[r * 72 + scol] =
                *(const bf16x8*)&kbase[(size_t)(base_k + r) * DM + scol];
        }
    };

    float* wzero = Wout + (size_t)h * TSEQ * TSEQ + (size_t)(q0 + wid * 16) * TSEQ;
    const int zcnt = 64 - nkt;          // zero k-tiles beyond the causal band
    int zdone = 0;
    const f32x4 zv = {0.f, 0.f, 0.f, 0.f};

    f32x4 lacc = {0.f, 0.f, 0.f, 0.f};
    stageKbig(0, 0);
    LGKM_BARRIER();
    for (int c = 0; c < nch; ++c) {
        const int b = c & 1;
        if (c + 1 < nch) stageKbig(c + 1, b ^ 1);
        const short* kb = lds + b * (128 * 72);
        #pragma unroll
        for (int t = 0; t < 2; ++t) {
            const int kt = c * 2 + t;
            if (kt >= nkt) break;
            f32x4 s4[4] = {};
            __builtin_amdgcn_s_setprio(1);
            #pragma unroll
            for (int ks = 0; ks < 2; ++ks) {
                bf16x8 qf = ks ? qf1 : qf0;
                #pragma unroll
                for (int n = 0; n < 4; ++n) {
                    bf16x8 kf = *(const bf16x8*)
                        &kb[(t * 64 + n * 16 + l15) * 72 + ks * 32 + lq * 8];
                    s4[n] = mfma16(kf, qf, s4[n]);
                }
            }
            __builtin_amdgcn_s_setprio(0);
            if (kt == qt) {  // diagonal: mask k > q
                #pragma unroll
                for (int n = 0; n < 4; ++n) {
                    int kb0 = kt * 64 + n * 16 + lq * 4;
                    #pragma unroll
                    for (int r = 0; r < 4; ++r)
                        lacc[n] += (kb0 + r <= myq) ? exp2f(s4[n][r] * SC) : 0.f;
                }
            } else {
                #pragma unroll
                for (int n = 0; n < 4; ++n)
                    #pragma unroll
                    for (int r = 0; r < 4; ++r)
                        lacc[n] += exp2f(s4[n][r] * SC);
            }
        }
        // this chunk's share of the zero tiles (NT streaming stores)
        {
            const int zgoal = (int)(((long)(c + 1) * zcnt) / nch);
            for (; zdone < zgoal; ++zdone) {
                const int kt = nkt + zdone;
                #pragma unroll
                for (int i = 0; i < 4; ++i)
                    __builtin_nontemporal_store(
                        zv, (f32x4*)(wzero + (size_t)(lq + i * 4) * TSEQ
                                     + kt * 64 + l15 * 4));
            }
        }
        LGKM_BARRIER();
    }
    float lsum = (lacc[0] + lacc[1]) + (lacc[2] + lacc[3]);
    lsum += __shfl_xor(lsum, 16);
    lsum += __shfl_xor(lsum, 32);
    const float nlog = -__log2f(lsum);   // fold 1/lsum into the exponent

    // ---- phase 2: recompute S, weight stores, P@V; reg-staged K (dbuf) and
    //      V (single buffer: last read is PV, barrier follows anyway) --------
    short* Ks2 = lds;                               // [2][64*72]
    short* Vs  = lds + 2 * 64 * 72;                 // [64*72]
    short* Psw = lds + 3 * 64 * 72 + wid * (16 * 72);

    bf16x8 krg0, krg1, vrg0, vrg1;      // staged tile (named: rule #20)
    auto loadKV = [&](int kt) {
        krg0 = *(const bf16x8*)&kbase[(size_t)(kt * 64 + srow) * DM + scol];
        krg1 = *(const bf16x8*)&kbase[(size_t)(kt * 64 + srow + 32) * DM + scol];
        vrg0 = *(const bf16x8*)&vbase[(size_t)srow * TSEQ + kt * 64 + scol];
        vrg1 = *(const bf16x8*)&vbase[(size_t)(srow + 32) * TSEQ + kt * 64 + scol];
    };
    auto writeK = [&](int b) {
        short* kd = Ks2 + b * (64 * 72);
        *(bf16x8*)&kd[srow * 72 + scol] = krg0;
        *(bf16x8*)&kd[(srow + 32) * 72 + scol] = krg1;
    };
    auto writeV = [&]() {
        *(bf16x8*)&Vs[srow * 72 + scol] = vrg0;
        *(bf16x8*)&Vs[(srow + 32) * 72 + scol] = vrg1;
    };

    float* wq = Wout + (size_t)h * TSEQ * TSEQ + (size_t)myq * TSEQ;
    f32x4 o[4] = {};
    loadKV(0);
    writeK(0);
    writeV();
    LGKM_BARRIER();
    for (int kt = 0; kt < nkt; ++kt) {
        const int b = kt & 1;
        const bool more = (kt + 1 < nkt);
        if (more) {
            loadKV(kt + 1);                       // issue next K/V early
            __builtin_amdgcn_sched_barrier(0);    // pin: loads above compute
        }
        f32x4 s4[4] = {};
        __builtin_amdgcn_s_setprio(1);
        #pragma unroll
        for (int ks = 0; ks < 2; ++ks) {
            bf16x8 qf = ks ? qf1 : qf0;
            #pragma unroll
            for (int n = 0; n < 4; ++n) {
                bf16x8 kf = *(const bf16x8*)
                    &Ks2[b * (64 * 72) + (n * 16 + l15) * 72 + ks * 32 + lq * 8];
                s4[n] = mfma16(kf, qf, s4[n]);
            }
        }
        __builtin_amdgcn_s_setprio(0);
        const bool diag = (kt == qt);
        #pragma unroll
        for (int n = 0; n < 4; ++n) {
            const int kb0 = kt * 64 + n * 16 + lq * 4;
            f32x4 p;
            #pragma unroll
            for (int r = 0; r < 4; ++r) {
                float e = exp2f(fmaf(s4[n][r], SC, nlog));  // normalized
                p[r] = (diag && (kb0 + r > myq)) ? 0.f : e;
            }
            *(f32x4*)(wq + kb0) = p;              // plain store: L2-merged
            uint2 pv;
            pv.x = pk2(p[0], p[1]);
            pv.y = pk2(p[2], p[3]);
            *(uint2*)&Psw[l15 * 72 + n * 16 + lq * 4] = pv;
        }
        // P @ V: A-frag = P (q rows) from per-wave Ps, B-frag = V^T from LDS
        __builtin_amdgcn_s_setprio(1);
        #pragma unroll
        for (int ks = 0; ks < 2; ++ks) {
            bf16x8 pf = *(bf16x8*)&Psw[l15 * 72 + ks * 32 + lq * 8];
            #pragma unroll
            for (int n = 0; n < 4; ++n) {
                bf16x8 vf = *(const bf16x8*)
                    &Vs[(n * 16 + l15) * 72 + ks * 32 + lq * 8];
                o[n] = mfma16(pf, vf, o[n]);
            }
        }
        __builtin_amdgcn_s_setprio(0);
        if (more) {
            __builtin_amdgcn_sched_barrier(0);
            LGKM_BARRIER();                       // all waves done reading Vs
            writeK(b ^ 1);                        // reg -> LDS, no vmcnt(0)
            writeV();
        }
        LGKM_BARRIER();                           // staging visible
    }

    // ---- epilogue: O (row = q0+wid*16+lq*4+r, col = h*64+n*16+l15) ----
    #pragma unroll
    for (int n = 0; n < 4; ++n) {
        int col = h * HDIM + n * 16 + l15;
        #pragma unroll
        for (int r = 0; r < 4; ++r) {
            int row = q0 + wid * 16 + lq * 4 + r;
            AttnO[(size_t)row * DM + col] = o[n][r];
        }
    }
}

extern "C" void kernel_launch(void* const* d_in, const int* in_sizes, int n_in,
                              void* d_out, int out_size, void* d_ws, size_t ws_size,
                              hipStream_t stream)
{
    const float* q_in = (const float*)d_in[0];
    const float* k_in = (const float*)d_in[1];
    const float* v_in = (const float*)d_in[2];
    // d_in[3] = causal mask (triu, k=1) — structure known, not read
    const float* Wq_w = (const float*)d_in[4];
    const float* Wq_b = (const float*)d_in[5];
    const float* Wk_w = (const float*)d_in[6];
    const float* Wk_b = (const float*)d_in[7];
    const float* Wv_w = (const float*)d_in[8];
    const float* Wv_b = (const float*)d_in[9];
    const float* W0_w = (const float*)d_in[10];
    const float* W0_b = (const float*)d_in[11];

    float* out  = (float*)d_out;                       // [4096][768] fp32
    float* wout = out + (size_t)TSEQ * DM;             // [12][4096][4096] fp32

    short* Qb = (short*)d_ws;                          // [4096][768] bf16
    short* Kb = Qb + (size_t)TSEQ * DM;                // [4096][768] bf16
    short* Vt = Kb + (size_t)TSEQ * DM;                // [768][4096] bf16 (V^T)
    float* AttnO = (float*)(Vt + (size_t)TSEQ * DM);   // [4096][768] fp32

    gemm_qkv<<<576, 512, 0, stream>>>(
        q_in, k_in, v_in, Wq_w, Wq_b, Wk_w, Wk_b, Wv_w, Wv_b, Qb, Kb, Vt);
    attn_fused<<<768, 256, 0, stream>>>(Qb, Kb, Vt, wout, AttnO);
    gemm_out<<<192, 512, 0, stream>>>(AttnO, W0_w, W0_b, out);
}